// Round 6
// baseline (40831.403 us; speedup 1.0000x reference)
//
#include <hip/hip_runtime.h>

// ---------------------------------------------------------------------------
// FarGAN wave head. R5: hide coherent-handoff (HBM-class) latency.
//   - 3 recurrent blocks (one/layer, 768 thr): LDS recurrence, Whh in VGPRs,
//     gi prefetched 4 steps deep, step loop unrolled x4 (static indexing).
//   - 2 GEMM blocks: h staged to LDS in 4-step double-buffered bursts
//     (prefetch ~2kcy ahead); gi written f16; flags at 32-step chunks.
// ---------------------------------------------------------------------------

#define B_    16
#define T_    50
#define SPS_  40
#define S_    8000
#define TS_   200
#define GRUIN_ 194
#define TWO_PI_F 6.2831853071795864769f

#define HRING_ 128           // h ring depth (steps)
#define CHK_   32            // chunk (steps)
#define NCHK_  250           // S_/CHK_
#define GIC_   3             // gi ring chunks

// workspace byte offsets
#define OFF_CTR    0
#define OFF_DV     4096
#define OFF_V      8192
#define OFF_SIN    16384     // 8000*16 f32
#define OFF_COS    528384
#define OFF_PE     1040384   // 16*50*64 f32
#define OFF_COND   1245184   // 16*200*128 f32
#define OFF_GBASE  2883584   // 200*36*64*4 f16
#define OFF_WF     6569984   // 5*216*512 bf16
#define OFF_HRING  7675904   // 2*128*3072 bf16
#define OFF_GI     9248768   // 2*3*32*2304 u64 (f16 gi)
#define OFF_SAMPLE 12787712  // 16*8000 f32
// end 13,299,712 B

typedef short s16x8 __attribute__((ext_vector_type(8)));
typedef float f32x4 __attribute__((ext_vector_type(4)));
typedef unsigned long long u64;

__device__ __forceinline__ short f2bf(float f) {
  unsigned u = __float_as_uint(f);
  return (short)((u + 0x7FFFu + ((u >> 16) & 1u)) >> 16);
}
__device__ __forceinline__ float sigm(float x) {
  return __fdividef(1.f, 1.f + __expf(-x));
}
__device__ __forceinline__ float tanhx(float x) {
  float e = __expf(2.f * x);
  return __fdividef(e - 1.f, e + 1.f);
}
#define AL(p)    __hip_atomic_load((p),  __ATOMIC_RELAXED, __HIP_MEMORY_SCOPE_AGENT)
#define AS(p,v)  __hip_atomic_store((p), (v), __ATOMIC_RELAXED, __HIP_MEMORY_SCOPE_AGENT)
#define BAR()    asm volatile("s_waitcnt lgkmcnt(0)\n\ts_barrier" ::: "memory")
#define BARVM()  asm volatile("s_waitcnt vmcnt(0) lgkmcnt(0)\n\ts_barrier" ::: "memory")

// ---------------------------------------------------------------------------
__global__ void k_frame(const float* __restrict__ feats,
                        const float* __restrict__ pembed,
                        const float* __restrict__ w1, const float* __restrict__ b1,
                        const float* __restrict__ w2, const float* __restrict__ b2,
                        char* ws) {
  const int bt = blockIdx.x, tid = threadIdx.x;   // 128 thr
  float* dvp = (float*)(ws + OFF_DV);
  float* vp  = (float*)(ws + OFF_V);
  float* pep = (float*)(ws + OFF_PE);
  float* cnd = (float*)(ws + OFF_COND);
  __shared__ float fin[112];
  __shared__ float h1[256];
  __shared__ int   sidx;
  if (tid == 0) {
    float f0 = feats[bt * 48 + 46], vo = feats[bt * 48 + 47];
    float period = fminf(fmaxf(256.f * exp2f(-(f0 + 2.f)), 32.f), 255.f);
    int idx = (int)rintf(period) - 32;
    float f0hz = 16000.f / fmaxf(period, 1.f);
    float v = fminf(fmaxf(vo, 0.f), 1.f);
    float delta = TWO_PI_F * fmaxf(f0hz, 60.f) * (1.f / 16000.f);
    dvp[bt] = delta * v; vp[bt] = v; sidx = idx;
  }
  __syncthreads();
  if (tid < 48) fin[tid] = feats[bt * 48 + tid];
  if (tid < 64) { float pv = pembed[sidx * 64 + tid]; fin[48 + tid] = pv; pep[bt * 64 + tid] = pv; }
  __syncthreads();
  #pragma unroll
  for (int rr = 0; rr < 2; ++rr) {
    int r = tid + rr * 128;
    const float* wr = w1 + r * 112;
    float acc = b1[r];
    #pragma unroll 4
    for (int k = 0; k < 112; ++k) acc += wr[k] * fin[k];
    h1[r] = 0.5f * acc * (1.f + erff(acc * 0.70710678118654752440f));
  }
  __syncthreads();
  const int b = bt / 50, t = bt - b * 50;
  #pragma unroll
  for (int rr = 0; rr < 4; ++rr) {
    int r = tid + rr * 128;
    const float* wr = w2 + r * 256;
    float acc = b2[r];
    #pragma unroll 4
    for (int k = 0; k < 256; ++k) acc += wr[k] * h1[k];
    int sf = r >> 7, c = r & 127;
    cnd[((b * 200) + (t * 4 + sf)) * 128 + c] = acc;
  }
}

// ---------------------------------------------------------------------------
__global__ void k_phase(char* ws) {
  const int b = blockIdx.x, tid = threadIdx.x;    // 256 thr
  const float* dvp = (const float*)(ws + OFF_DV);
  float* sinA = (float*)(ws + OFF_SIN);
  float* cosA = (float*)(ws + OFF_COS);
  __shared__ float ps[200], dvs[200];
  if (tid == 0) {
    float c = 0.f;
    for (int ts = 0; ts < 200; ++ts) {
      float d = dvp[b * 50 + (ts >> 2)];
      dvs[ts] = d;
      float inc = d * (float)SPS_;
      c = c + inc;
      ps[ts] = fmodf(c - inc, TWO_PI_F);
    }
  }
  __syncthreads();
  for (int i = tid; i < S_; i += 256) {
    int ts = i / 40, k = i - ts * 40;
    float ph = ps[ts] + dvs[ts] * (float)k;
    sinA[(size_t)i * 16 + b] = sinf(ph);
    cosA[(size_t)i * 16 + b] = cosf(ph);
  }
}

// ---------------------------------------------------------------------------
// gbase = bih0 + Wc@cond + Wp@pe, f16, MFMA D-tile layout
__global__ void k_gbase(const float* __restrict__ wih0,
                        const float* __restrict__ bih0, char* ws) {
  const int ts = blockIdx.x, tid = threadIdx.x;   // 200 blocks, 256 thr
  const int t = ts >> 2;
  const float* cnd = (const float*)(ws + OFF_COND);
  const float* pep = (const float*)(ws + OFF_PE);
  _Float16* gbp = (_Float16*)(ws + OFF_GBASE);
  __shared__ float c_s[16][128];
  __shared__ float p_s[16][64];
  for (int i = tid; i < 2048; i += 256) c_s[i >> 7][i & 127] = cnd[((i >> 7) * 200 + ts) * 128 + (i & 127)];
  for (int i = tid; i < 1024; i += 256) p_s[i >> 6][i & 63] = pep[((i >> 6) * 50 + t) * 64 + (i & 63)];
  __syncthreads();
  for (int i = tid; i < 9216; i += 256) {
    int row = i >> 4, b = i & 15;
    const float* wr = wih0 + (size_t)row * GRUIN_;
    float acc = bih0[row];
    #pragma unroll 4
    for (int k = 0; k < 128; ++k) acc += wr[k] * c_s[b][k];
    #pragma unroll 4
    for (int k = 0; k < 64; ++k) acc += wr[128 + k] * p_s[b][k];
    int nt = row >> 4, l15 = row & 15;
    int lane = l15 | ((b >> 2) << 4), j = b & 3;
    gbp[((size_t)(ts * 36 + nt) * 64 + lane) * 4 + j] = (_Float16)acc;
  }
}

// ---------------------------------------------------------------------------
// pack 5 matrices into bf16 B-frags: 0=whh0 1=whh1 2=whh2 3=wih1 4=wih2
__global__ void k_wprep(const float* __restrict__ whh0, const float* __restrict__ whh1,
                        const float* __restrict__ whh2, const float* __restrict__ wih1,
                        const float* __restrict__ wih2, char* ws) {
  const int blk = blockIdx.x;           // 1080 blocks, 64 thr
  const int mat = blk / 216, rem = blk - mat * 216;
  const int nt = rem / 6, kt = rem - nt * 6;
  const int lane = threadIdx.x;
  const float* W = (mat == 0) ? whh0 : (mat == 1) ? whh1 : (mat == 2) ? whh2
                  : (mat == 3) ? wih1 : wih2;
  short* dst = (short*)(ws + OFF_WF) + ((size_t)(mat * 36 + nt) * 6 + kt) * 512 + lane * 8;
  const int row = nt * 16 + (lane & 15);
  const int g = lane >> 4;
  #pragma unroll
  for (int e = 0; e < 8; ++e) {
    int k = kt * 32 + 16 * (e >> 2) + 4 * g + (e & 3);
    dst[e] = f2bf(W[(size_t)row * 192 + k]);
  }
}

// ---------------------------------------------------------------------------
// K4: 5 persistent blocks x 768 thr (12 waves).
// ---------------------------------------------------------------------------
__global__ __launch_bounds__(768, 1)
void k_gru(char* ws, const float* __restrict__ wih0,
           const float* __restrict__ bhh0, const float* __restrict__ bhh1,
           const float* __restrict__ bhh2, const float* __restrict__ bih1,
           const float* __restrict__ bih2, const float* __restrict__ outw) {
  const int blk = blockIdx.x;
  const int tid = threadIdx.x;
  const int ut = tid >> 6, lane = tid & 63, lg = lane >> 4, l15 = lane & 15;

  int* ctr = (int*)ws;   // hcnt:+l*32 | gicnt:+64+(m-1)*32 | gprog:+128+l*32 | rprog:+192+(m-1)*32
  const short* wf = (const short*)(ws + OFF_WF);
  short* hring    = (short*)(ws + OFF_HRING);
  u64*   giring   = (u64*)(ws + OFF_GI);
  float* sample   = (float*)(ws + OFF_SAMPLE);

  __shared__ __align__(16) short hbuf[2][3072];       // recurrent dbuf
  __shared__ __align__(16) short lbuf[2][4][3072];    // GEMM staging (48KB)
  __shared__ float plds[2][12][16];

  const int rdoff = (lane ^ ((lane >> 4) & 3)) * 8;   // swizzled frag read

  if (blk < 3) {
    // =========================== recurrent block ===========================
    const int l = blk;
    const float* sinA = (const float*)(ws + OFF_SIN);
    const float* cosA = (const float*)(ws + OFF_COS);
    const u64* gbp64  = (const u64*)(ws + OFF_GBASE);
    const float* bhh = (l == 0) ? bhh0 : (l == 1) ? bhh1 : bhh2;

    s16x8 WH[3][6];
    float bh[3];
    #pragma unroll
    for (int g = 0; g < 3; ++g) {
      const int nt = g * 12 + ut;
      #pragma unroll
      for (int kt = 0; kt < 6; ++kt)
        WH[g][kt] = *(const s16x8*)(wf + ((size_t)l * 216 + nt * 6 + kt) * 512 + lane * 8);
      bh[g] = bhh[g * 192 + 16 * ut + l15];
    }
    float wsn[3], wcs[3];
    if (l == 0) {
      #pragma unroll
      for (int g = 0; g < 3; ++g) {
        int row = g * 192 + 16 * ut + l15;
        wsn[g] = wih0[(size_t)row * GRUIN_ + 192];
        wcs[g] = wih0[(size_t)row * GRUIN_ + 193];
      }
    }
    const float ow = (l == 2) ? outw[16 * ut + l15] : 0.f;

    for (int i = tid; i < 1536; i += 768) ((u64*)hbuf)[i] = 0;
    __syncthreads();

    f32x4 h = {0, 0, 0, 0};
    f32x4 gbf[3];
    u64 gcur[4][3], gnx[4][3];
    f32x4 s4g[4], c4g[4];
    // h' write coords (swizzled)
    const int kt_w = ut >> 1;
    const int e_   = ((ut & 1) << 2) | (l15 & 3);
    const int q_   = l15 >> 2;

    const u64* gib = (l > 0) ? giring + (size_t)(l - 1) * (GIC_ * CHK_ * 2304) : (const u64*)0;

    for (int tb = 0; tb < S_; tb += 4) {
      // ================= group head =================
      if ((tb & 31) == 0) {
        if (l < 2) {
          BARVM();                              // drain publishes h_0..h_{tb-1}
          if (tid == 0) {
            AS(ctr + l * 32, tb);               // hcnt = tb
            if (tb >= 128) {
              const int need = tb - 96;
              while (AL(ctr + 128 + l * 32) < need) __builtin_amdgcn_s_sleep(4);
            }
          }
        }
        if (l > 0) {
          if (tid == 0) {
            AS(ctr + 192 + (l - 1) * 32, tb >> 5);   // rprog
            int tgt = (tb >> 5) + 2; if (tgt > NCHK_) tgt = NCHK_;
            while (AL(ctr + 64 + (l - 1) * 32) < tgt) __builtin_amdgcn_s_sleep(2);
          }
        }
        __syncthreads();
      }
      // gi: rotate prefetch (4 deep)
      if (l > 0) {
        if (tb == 0) {
          #pragma unroll
          for (int s = 0; s < 4; ++s) {
            const u64* p = gib + (size_t)(((s >> 5) % GIC_) * CHK_ + s) * 2304;
            #pragma unroll
            for (int g = 0; g < 3; ++g) gcur[s][g] = AL(p + (12 * g + ut) * 64 + lane);
          }
        } else {
          #pragma unroll
          for (int s = 0; s < 4; ++s)
            #pragma unroll
            for (int g = 0; g < 3; ++g) gcur[s][g] = gnx[s][g];
        }
        #pragma unroll
        for (int s = 0; s < 4; ++s) {
          const int tn = tb + 4 + s;           // may exceed S_-1: reads stale ring, unused
          const u64* p = gib + (size_t)(((tn >> 5) % GIC_) * CHK_ + (tn & 31)) * 2304;
          #pragma unroll
          for (int g = 0; g < 3; ++g) gnx[s][g] = AL(p + (12 * g + ut) * 64 + lane);
        }
      }
      if (l == 0) {
        #pragma unroll
        for (int s = 0; s < 4; ++s) {
          s4g[s] = *(const f32x4*)(sinA + (size_t)(tb + s) * 16 + lg * 4);
          c4g[s] = *(const f32x4*)(cosA + (size_t)(tb + s) * 16 + lg * 4);
        }
        if ((tb % 40) == 0) {
          int ts = tb / 40;
          #pragma unroll
          for (int g = 0; g < 3; ++g) {
            union { u64 u; _Float16 hh[4]; } up;
            up.u = gbp64[(size_t)(ts * 36 + 12 * g + ut) * 64 + lane];
            f32x4 v; v[0]=(float)up.hh[0]; v[1]=(float)up.hh[1]; v[2]=(float)up.hh[2]; v[3]=(float)up.hh[3];
            gbf[g] = v;
          }
        }
      }
      // ================= 4 sub-steps =================
      #pragma unroll
      for (int s = 0; s < 4; ++s) {
        const int t = tb + s;
        // sample store for t-1 (layer2)
        if (l == 2 && tid < 16 && !(tb == 0 && s == 0)) {
          float sm = 0.f;
          #pragma unroll
          for (int uu = 0; uu < 12; ++uu) sm += plds[(s & 1) ^ 1][uu][tid];
          sample[(size_t)tid * S_ + (t - 1)] = sm;
        }
        // LDS -> A-frags
        s16x8 hf[6];
        #pragma unroll
        for (int kt = 0; kt < 6; ++kt)
          hf[kt] = *(const s16x8*)(hbuf[s & 1] + kt * 512 + rdoff);
        // MFMA
        f32x4 acc[3];
        #pragma unroll
        for (int g = 0; g < 3; ++g) { f32x4 a = {bh[g], bh[g], bh[g], bh[g]}; acc[g] = a; }
        #pragma unroll
        for (int kt = 0; kt < 6; ++kt)
          #pragma unroll
          for (int g = 0; g < 3; ++g)
            acc[g] = __builtin_amdgcn_mfma_f32_16x16x32_bf16(hf[kt], WH[g][kt], acc[g], 0, 0, 0);
        // gates
        f32x4 gr, gz, gn;
        if (l == 0) {
          gr = gbf[0] + s4g[s] * wsn[0] + c4g[s] * wcs[0];
          gz = gbf[1] + s4g[s] * wsn[1] + c4g[s] * wcs[1];
          gn = gbf[2] + s4g[s] * wsn[2] + c4g[s] * wcs[2];
        } else {
          union { u64 u; _Float16 hh[4]; } u0, u1, u2;
          u0.u = gcur[s][0]; u1.u = gcur[s][1]; u2.u = gcur[s][2];
          #pragma unroll
          for (int j = 0; j < 4; ++j) { gr[j]=(float)u0.hh[j]; gz[j]=(float)u1.hh[j]; gn[j]=(float)u2.hh[j]; }
        }
        #pragma unroll
        for (int j = 0; j < 4; ++j) {
          float r = sigm(gr[j] + acc[0][j]);
          float z = sigm(gz[j] + acc[1][j]);
          float n = tanhx(gn[j] + r * acc[2][j]);
          h[j] = n + z * (h[j] - n);
        }
        // write h' -> swizzled A-frag LDS (other buffer)
        {
          short* wb = hbuf[(s & 1) ^ 1] + kt_w * 512;
          #pragma unroll
          for (int j = 0; j < 4; ++j) {
            int b16 = ((4 * lg + j) | (q_ << 4)) ^ q_;
            wb[b16 * 8 + e_] = f2bf(h[j]);
          }
        }
        // head partials (layer2)
        if (l == 2) {
          #pragma unroll
          for (int j = 0; j < 4; ++j) {
            float p = ow * h[j];
            p += __shfl_xor(p, 1); p += __shfl_xor(p, 2);
            p += __shfl_xor(p, 4); p += __shfl_xor(p, 8);
            if (l15 == 0) plds[s & 1][ut][lg * 4 + j] = p;
          }
        }
        BAR();
        // publish h_t (layers 0,1): h' now complete in hbuf[(s&1)^1]
        if (l < 2) {
          u64 v = ((const u64*)(hbuf[(s & 1) ^ 1]))[tid];
          u64* rd = (u64*)(hring + (size_t)(l * HRING_ + (t & (HRING_ - 1))) * 3072) + tid;
          AS(rd, v);
        }
      }
    }
    // tail
    if (l < 2) {
      asm volatile("s_waitcnt vmcnt(0)" ::: "memory");
      __syncthreads();
      if (tid == 0) AS(ctr + l * 32, S_);
    } else if (tid < 16) {
      float sm = 0.f;
      #pragma unroll
      for (int uu = 0; uu < 12; ++uu) sm += plds[1][uu][tid];   // (S_-1)&1 == 1
      sample[(size_t)tid * S_ + (S_ - 1)] = sm;
    }
  } else {
    // ============================= GEMM block ==============================
    const int m = blk - 2;          // target layer 1 or 2
    const int lsrc = m - 1;         // source h ring
    const float* bih = (m == 1) ? bih1 : bih2;

    s16x8 WB[3][6];
    float bi[3];
    #pragma unroll
    for (int g = 0; g < 3; ++g) {
      const int nt = 12 * g + ut;
      #pragma unroll
      for (int kt = 0; kt < 6; ++kt)
        WB[g][kt] = *(const s16x8*)(wf + ((size_t)(2 + m) * 216 + nt * 6 + kt) * 512 + lane * 8);
      bi[g] = bih[nt * 16 + l15];
    }

    for (int c = 0; c < NCHK_; ++c) {
      if (tid == 0) {
        while (AL(ctr + lsrc * 32) < CHK_ * (c + 1)) __builtin_amdgcn_s_sleep(4);
        while (AL(ctr + 192 + (m - 1) * 32) < c - 2) __builtin_amdgcn_s_sleep(4);
      }
      __syncthreads();

      // stage subtile 0 (4 steps) into regs
      u64 R[4];
      {
        const u64* sb = (const u64*)(hring + (size_t)(lsrc * HRING_ + ((CHK_ * c) & (HRING_ - 1))) * 3072);
        #pragma unroll
        for (int q = 0; q < 4; ++q) R[q] = AL(sb + q * 768 + tid);
      }
      for (int st = 0; st < 8; ++st) {
        // regs -> LDS (compiler inserts counted vmcnt for R)
        u64* lb = (u64*)(lbuf[st & 1]);
        #pragma unroll
        for (int q = 0; q < 4; ++q) lb[q * 768 + tid] = R[q];
        __syncthreads();
        if (st < 7) {
          const u64* nb = (const u64*)(hring + (size_t)(lsrc * HRING_ + ((CHK_ * c + 4 * (st + 1)) & (HRING_ - 1))) * 3072);
          #pragma unroll
          for (int q = 0; q < 4; ++q) R[q] = AL(nb + q * 768 + tid);
        }
        #pragma unroll
        for (int s4 = 0; s4 < 4; ++s4) {
          const int t = CHK_ * c + 4 * st + s4;
          s16x8 hf[6];
          #pragma unroll
          for (int kt = 0; kt < 6; ++kt)
            hf[kt] = *(const s16x8*)(lbuf[st & 1][s4] + kt * 512 + rdoff);
          u64* dst = giring + (size_t)(m - 1) * (GIC_ * CHK_ * 2304)
                   + (size_t)((c % GIC_) * CHK_ + (t & 31)) * 2304 + lane;
          #pragma unroll
          for (int g = 0; g < 3; ++g) {
            f32x4 a = {bi[g], bi[g], bi[g], bi[g]};
            #pragma unroll
            for (int kt = 0; kt < 6; ++kt)
              a = __builtin_amdgcn_mfma_f32_16x16x32_bf16(hf[kt], WB[g][kt], a, 0, 0, 0);
            union { _Float16 hh[4]; u64 u; } pk;
            #pragma unroll
            for (int j = 0; j < 4; ++j) pk.hh[j] = (_Float16)a[j];
            AS(dst + (12 * g + ut) * 64, pk.u);
          }
        }
      }
      // chunk end: drain gi stores, publish
      asm volatile("s_waitcnt vmcnt(0)" ::: "memory");
      __syncthreads();
      if (tid == 0) {
        AS(ctr + 64 + (m - 1) * 32, c + 1);          // gicnt
        AS(ctr + 128 + lsrc * 32, CHK_ * (c + 1));   // gprog
      }
    }
  }
}

// ---------------------------------------------------------------------------
__global__ void k_final(char* ws, const float* __restrict__ noise,
                        const float* __restrict__ outb, const float* __restrict__ lgain,
                        float* __restrict__ out) {
  int i = blockIdx.x * 256 + threadIdx.x;
  if (i >= B_ * S_) return;
  int b = i / S_, s = i - b * S_;
  const float* sample = (const float*)(ws + OFF_SAMPLE);
  const float* vp     = (const float*)(ws + OFF_V);
  float smp = sample[(size_t)b * S_ + s] + outb[0];
  float v = vp[b * 50 + s / 160];
  float noisy = 0.6f * smp + 0.4f * (noise[(size_t)b * S_ + s] * 0.003f);
  float sm2 = v * smp + (1.f - v) * noisy;
  float wave = fminf(fmaxf(sm2, -1.f), 1.f);
  float gain = fminf(fmaxf(expf(lgain[0]), 0.5f), 1.5f);
  out[i] = 1.1f * tanhf(0.9f * gain * wave);
}

// ---------------------------------------------------------------------------
extern "C" void kernel_launch(void* const* d_in, const int* in_sizes, int n_in,
                              void* d_out, int out_size, void* d_ws, size_t ws_size,
                              hipStream_t stream) {
  (void)in_sizes; (void)n_in; (void)out_size; (void)ws_size;
  const float* feats  = (const float*)d_in[0];
  const float* noise  = (const float*)d_in[1];
  const float* pembed = (const float*)d_in[2];
  const float* fpw1   = (const float*)d_in[3];
  const float* fpb1   = (const float*)d_in[4];
  const float* fpw2   = (const float*)d_in[5];
  const float* fpb2   = (const float*)d_in[6];
  const float* outw   = (const float*)d_in[7];
  const float* outb   = (const float*)d_in[8];
  const float* lgain  = (const float*)d_in[9];
  const float* wih0   = (const float*)d_in[10];
  const float* whh0   = (const float*)d_in[11];
  const float* bih0   = (const float*)d_in[12];
  const float* bhh0   = (const float*)d_in[13];
  const float* wih1   = (const float*)d_in[14];
  const float* whh1   = (const float*)d_in[15];
  const float* bih1   = (const float*)d_in[16];
  const float* bhh1   = (const float*)d_in[17];
  const float* wih2   = (const float*)d_in[18];
  const float* whh2   = (const float*)d_in[19];
  const float* bih2   = (const float*)d_in[20];
  const float* bhh2   = (const float*)d_in[21];
  char* ws = (char*)d_ws;
  float* out = (float*)d_out;

  hipMemsetAsync(ws, 0, 1024, stream);
  hipLaunchKernelGGL(k_wprep, dim3(1080), dim3(64), 0, stream,
                     whh0, whh1, whh2, wih1, wih2, ws);
  hipLaunchKernelGGL(k_frame, dim3(B_ * T_), dim3(128), 0, stream,
                     feats, pembed, fpw1, fpb1, fpw2, fpb2, ws);
  hipLaunchKernelGGL(k_phase, dim3(B_), dim3(256), 0, stream, ws);
  hipLaunchKernelGGL(k_gbase, dim3(TS_), dim3(256), 0, stream, wih0, bih0, ws);
  hipLaunchKernelGGL(k_gru, dim3(5), dim3(768), 0, stream, ws, wih0,
                     bhh0, bhh1, bhh2, bih1, bih2, outw);
  hipLaunchKernelGGL(k_final, dim3((B_ * S_ + 255) / 256), dim3(256), 0, stream,
                     ws, noise, outb, lgain, out);
}

// Round 7
// 35146.963 us; speedup vs baseline: 1.1617x; 1.1617x over previous
//
#include <hip/hip_runtime.h>

// ---------------------------------------------------------------------------
// FarGAN wave head. R6: strict ONE-WAY pipeline with large slack.
//   chain: L0r -> G1 -> L1r -> G2 -> L2r   (5 persistent blocks, 768 thr)
//   h rings 256 steps, gi rings 96 steps; consumers need +8..16 lead only;
//   producers free-run ~80-190 ahead. All waits cached watermarks (rarely
//   re-read). Whh/Wih register-resident per block; raw lgkm-only barriers.
// ---------------------------------------------------------------------------

#define B_ 16
#define S_ 8000
#define GRUIN_ 194
#define TWO_PI_F 6.2831853071795864769f

#define HR_ 256
#define GR_ 96

// ws offsets (bytes)
#define OFF_CTR    0
#define OFF_DV     4096
#define OFF_V      8192
#define OFF_SIN    16384      // 8000*16 f32
#define OFF_COS    528384
#define OFF_PE     1040384    // 16*50*64 f32
#define OFF_COND   1245184    // 16*200*128 f32
#define OFF_XF     2883584    // 200*6*512 bf16 (cond|pe A-frags)
#define OFF_WF     4112384    // 6*216*512 bf16 (B-frags)
#define OFF_H0     5439488    // 256*3072 bf16
#define OFF_H1     7012352
#define OFF_GI1    8585216    // 96*2304 u64 (f16 gi)
#define OFF_GI2    10354688
#define OFF_SAMPLE 12124160   // 16*8000 f32
// end 12,636,160

// counters (int index into ctr[])
#define C_H0   0
#define C_H1   32
#define C_GIP1 64
#define C_GIP2 96
#define C_GEM1 128
#define C_GEM2 160
#define C_RP2  192

typedef short s16x8 __attribute__((ext_vector_type(8)));
typedef float f32x4 __attribute__((ext_vector_type(4)));
typedef unsigned long long u64;

__device__ __forceinline__ short f2bf(float f) {
  unsigned u = __float_as_uint(f);
  return (short)((u + 0x7FFFu + ((u >> 16) & 1u)) >> 16);
}
__device__ __forceinline__ float sigm(float x) {
  return __fdividef(1.f, 1.f + __expf(-x));
}
__device__ __forceinline__ float tanhx(float x) {
  float e = __expf(2.f * x);
  return __fdividef(e - 1.f, e + 1.f);
}
#define AL(p)   __hip_atomic_load((p),  __ATOMIC_RELAXED, __HIP_MEMORY_SCOPE_AGENT)
#define AS(p,v) __hip_atomic_store((p), (v), __ATOMIC_RELAXED, __HIP_MEMORY_SCOPE_AGENT)
#define BAR()   asm volatile("s_waitcnt lgkmcnt(0)\n\ts_barrier" ::: "memory")
#define BARVM() asm volatile("s_waitcnt vmcnt(0) lgkmcnt(0)\n\ts_barrier" ::: "memory")

// ---------------------------------------------------------------------------
__global__ void k_frame(const float* __restrict__ feats,
                        const float* __restrict__ pembed,
                        const float* __restrict__ w1, const float* __restrict__ b1,
                        const float* __restrict__ w2, const float* __restrict__ b2,
                        char* ws) {
  const int bt = blockIdx.x, tid = threadIdx.x;   // 128 thr
  float* dvp = (float*)(ws + OFF_DV);
  float* vp  = (float*)(ws + OFF_V);
  float* pep = (float*)(ws + OFF_PE);
  float* cnd = (float*)(ws + OFF_COND);
  __shared__ float fin[112];
  __shared__ float h1[256];
  __shared__ int   sidx;
  if (tid == 0) {
    float f0 = feats[bt * 48 + 46], vo = feats[bt * 48 + 47];
    float period = fminf(fmaxf(256.f * exp2f(-(f0 + 2.f)), 32.f), 255.f);
    int idx = (int)rintf(period) - 32;
    float f0hz = 16000.f / fmaxf(period, 1.f);
    float v = fminf(fmaxf(vo, 0.f), 1.f);
    float delta = TWO_PI_F * fmaxf(f0hz, 60.f) * (1.f / 16000.f);
    dvp[bt] = delta * v; vp[bt] = v; sidx = idx;
  }
  __syncthreads();
  if (tid < 48) fin[tid] = feats[bt * 48 + tid];
  if (tid < 64) { float pv = pembed[sidx * 64 + tid]; fin[48 + tid] = pv; pep[bt * 64 + tid] = pv; }
  __syncthreads();
  #pragma unroll
  for (int rr = 0; rr < 2; ++rr) {
    int r = tid + rr * 128;
    const float* wr = w1 + r * 112;
    float acc = b1[r];
    #pragma unroll 4
    for (int k = 0; k < 112; ++k) acc += wr[k] * fin[k];
    h1[r] = 0.5f * acc * (1.f + erff(acc * 0.70710678118654752440f));
  }
  __syncthreads();
  const int b = bt / 50, t = bt - b * 50;
  #pragma unroll
  for (int rr = 0; rr < 4; ++rr) {
    int r = tid + rr * 128;
    const float* wr = w2 + r * 256;
    float acc = b2[r];
    #pragma unroll 4
    for (int k = 0; k < 256; ++k) acc += wr[k] * h1[k];
    int sf = r >> 7, c = r & 127;
    cnd[((b * 200) + (t * 4 + sf)) * 128 + c] = acc;
  }
}

// ---------------------------------------------------------------------------
__global__ void k_phase(char* ws) {
  const int b = blockIdx.x, tid = threadIdx.x;    // 256 thr
  const float* dvp = (const float*)(ws + OFF_DV);
  float* sinA = (float*)(ws + OFF_SIN);
  float* cosA = (float*)(ws + OFF_COS);
  __shared__ float ps[200], dvs[200];
  if (tid == 0) {
    float c = 0.f;
    for (int ts = 0; ts < 200; ++ts) {
      float d = dvp[b * 50 + (ts >> 2)];
      dvs[ts] = d;
      float inc = d * 40.f;
      c = c + inc;
      ps[ts] = fmodf(c - inc, TWO_PI_F);
    }
  }
  __syncthreads();
  for (int i = tid; i < S_; i += 256) {
    int ts = i / 40, k = i - ts * 40;
    float ph = ps[ts] + dvs[ts] * (float)k;
    sinA[(size_t)i * 16 + b] = sinf(ph);
    cosA[(size_t)i * 16 + b] = cosf(ph);
  }
}

// ---------------------------------------------------------------------------
// pack [cond(128)|pe(64)] per ts into bf16 A-frags (same k-map as wprep)
__global__ void k_xpack(char* ws) {
  const int ts = blockIdx.x, tid = threadIdx.x;   // 200 blocks, 256 thr
  const int t = ts >> 2;
  const float* cnd = (const float*)(ws + OFF_COND);
  const float* pep = (const float*)(ws + OFF_PE);
  short* xf = (short*)(ws + OFF_XF) + (size_t)ts * 3072;
  for (int i = tid; i < 3072; i += 256) {
    int kt = i >> 9, r = i & 511, lane = r >> 3, e = r & 7;
    int k = kt * 32 + 16 * (e >> 2) + 4 * (lane >> 4) + (e & 3);
    int b = lane & 15;
    float v = (k < 128) ? cnd[((b * 200) + ts) * 128 + k]
                        : pep[(b * 50 + t) * 64 + (k - 128)];
    xf[i] = f2bf(v);
  }
}

// ---------------------------------------------------------------------------
// pack 6 matrices into bf16 B-frags: 0=whh0 1=whh1 2=whh2 3=wih1 4=wih2 5=wih0[:, :192]
__global__ void k_wprep(const float* __restrict__ whh0, const float* __restrict__ whh1,
                        const float* __restrict__ whh2, const float* __restrict__ wih1,
                        const float* __restrict__ wih2, const float* __restrict__ wih0,
                        char* ws) {
  const int blk = blockIdx.x;           // 1296 blocks, 64 thr
  const int mat = blk / 216, rem = blk - mat * 216;
  const int nt = rem / 6, kt = rem - nt * 6;
  const int lane = threadIdx.x;
  const float* W; int stride;
  if (mat == 0)      { W = whh0; stride = 192; }
  else if (mat == 1) { W = whh1; stride = 192; }
  else if (mat == 2) { W = whh2; stride = 192; }
  else if (mat == 3) { W = wih1; stride = 192; }
  else if (mat == 4) { W = wih2; stride = 192; }
  else               { W = wih0; stride = 194; }
  short* dst = (short*)(ws + OFF_WF) + ((size_t)(mat * 216) + nt * 6 + kt) * 512 + lane * 8;
  const int row = nt * 16 + (lane & 15);
  const int g = lane >> 4;
  #pragma unroll
  for (int e = 0; e < 8; ++e) {
    int k = kt * 32 + 16 * (e >> 2) + 4 * g + (e & 3);
    dst[e] = f2bf(W[(size_t)row * stride + k]);
  }
}

// ---------------------------------------------------------------------------
// K4: 5 persistent blocks x 768 thr: 0=L0r 1=G1 2=L1r 3=G2 4=L2r
// ---------------------------------------------------------------------------
__global__ __launch_bounds__(768, 1)
void k_gru(char* ws, const float* __restrict__ wih0, const float* __restrict__ bih0,
           const float* __restrict__ bhh0, const float* __restrict__ bhh1,
           const float* __restrict__ bhh2, const float* __restrict__ bih1,
           const float* __restrict__ bih2, const float* __restrict__ outw) {
  const int blk = blockIdx.x;
  const int tid = threadIdx.x;
  const int ut = tid >> 6, lane = tid & 63, lg = lane >> 4, l15 = lane & 15;

  int* ctr = (int*)ws;
  const short* wf = (const short*)(ws + OFF_WF);
  float* sample   = (float*)(ws + OFF_SAMPLE);

  __shared__ __align__(16) u64 hstage[2][4][768];   // G staging, 48KB
  __shared__ __align__(16) short hbuf[2][3072];     // rec dbuf, 12KB
  __shared__ float plds[2][12][16];
  __shared__ int bc;

  const int rdoff = (lane ^ ((lane >> 4) & 3)) * 8;

  if ((blk & 1) == 0) {
    // ============================ recurrent ================================
    const int l = blk >> 1;
    const float* sinA = (const float*)(ws + OFF_SIN);
    const float* cosA = (const float*)(ws + OFF_COS);
    const short* xfb  = (const short*)(ws + OFF_XF);
    const float* bhh = (l == 0) ? bhh0 : (l == 1) ? bhh1 : bhh2;
    const u64* girp = (l == 1) ? (const u64*)(ws + OFF_GI1)
                    : (l == 2) ? (const u64*)(ws + OFF_GI2) : (const u64*)0;
    u64* hpub = (l == 0) ? (u64*)(ws + OFF_H0) : (l == 1) ? (u64*)(ws + OFF_H1) : (u64*)0;
    const int hctr = (l == 0) ? C_H0 : C_H1;
    const int gipc = (l == 1) ? C_GIP1 : C_GIP2;
    const int gemc = (l == 0) ? C_GEM1 : C_GEM2;

    s16x8 WH[3][6];
    float bh[3];
    #pragma unroll
    for (int g = 0; g < 3; ++g) {
      const int nt = g * 12 + ut;
      #pragma unroll
      for (int kt = 0; kt < 6; ++kt)
        WH[g][kt] = *(const s16x8*)(wf + ((size_t)(l * 216) + nt * 6 + kt) * 512 + lane * 8);
      bh[g] = bhh[g * 192 + 16 * ut + l15];
    }
    float wsn[3], wcs[3], bi0[3];
    if (l == 0) {
      #pragma unroll
      for (int g = 0; g < 3; ++g) {
        int row = g * 192 + 16 * ut + l15;
        wsn[g] = wih0[(size_t)row * GRUIN_ + 192];
        wcs[g] = wih0[(size_t)row * GRUIN_ + 193];
        bi0[g] = bih0[row];
      }
    }
    const float ow = (l == 2) ? outw[16 * ut + l15] : 0.f;

    for (int i = tid; i < 1536; i += 768) ((u64*)hbuf)[i] = 0;
    __syncthreads();

    f32x4 h = {0, 0, 0, 0};
    f32x4 gbf[3];
    u64 gpf[2][2][3];          // [pair][idx][gate]
    int giavail = 0, gemavail = 0;
    const int kt_w = ut >> 1;
    const int e_   = ((ut & 1) << 2) | (l15 & 3);
    const int q_   = l15 >> 2;

    // prime gi prefetch
    if (l > 0) {
      if (tid == 0) {
        int v = AL(ctr + gipc);
        while (v < 16) { __builtin_amdgcn_s_sleep(2); v = AL(ctr + gipc); }
        bc = v;
      }
      __syncthreads();
      giavail = bc;
      __syncthreads();
      #pragma unroll
      for (int p = 0; p < 2; ++p)
        #pragma unroll
        for (int ss = 0; ss < 2; ++ss)
          #pragma unroll
          for (int g = 0; g < 3; ++g)
            gpf[p][ss][g] = AL(girp + (size_t)((2 * p + ss) % GR_) * 2304 + (12 * g + ut) * 64 + lane);
    }

    for (int tb = 0; tb < S_; tb += 4) {
      // ---- waits (cached watermarks, rarely touched) ----
      if (l > 0 && (tb & 7) == 0) {
        int tgt = tb + 16; if (tgt > S_) tgt = S_;
        if (giavail < tgt) {
          if (tid == 0) {
            int v = AL(ctr + gipc);
            while (v < tgt) { __builtin_amdgcn_s_sleep(2); v = AL(ctr + gipc); }
            bc = v;
          }
          __syncthreads(); giavail = bc; __syncthreads();
        }
      }
      if (l < 2 && (tb & 63) == 0 && tb >= 192) {
        int tgt = tb - 128;
        if (gemavail < tgt) {
          if (tid == 0) {
            int v = AL(ctr + gemc);
            while (v < tgt) { __builtin_amdgcn_s_sleep(2); v = AL(ctr + gemc); }
            bc = v;
          }
          __syncthreads(); gemavail = bc; __syncthreads();
        }
      }
      if (l == 2 && (tb & 63) == 0 && tid == 0) AS(ctr + C_RP2, tb);

      // ---- gbase GEMM every 40 steps (layer 0) ----
      if (l == 0 && tb % 40 == 0) {
        int ts = tb / 40;
        const short* xp = xfb + (size_t)ts * 3072;
        s16x8 xfr[6];
        #pragma unroll
        for (int kt = 0; kt < 6; ++kt) xfr[kt] = *(const s16x8*)(xp + kt * 512 + lane * 8);
        #pragma unroll
        for (int g = 0; g < 3; ++g) {
          const int nt = g * 12 + ut;
          f32x4 a = {bi0[g], bi0[g], bi0[g], bi0[g]};
          #pragma unroll
          for (int kt = 0; kt < 6; ++kt) {
            s16x8 wfr = *(const s16x8*)(wf + ((size_t)(5 * 216) + nt * 6 + kt) * 512 + lane * 8);
            a = __builtin_amdgcn_mfma_f32_16x16x32_bf16(xfr[kt], wfr, a, 0, 0, 0);
          }
          gbf[g] = a;
        }
      }

      // ---- 4 substeps ----
      #pragma unroll
      for (int s = 0; s < 4; ++s) {
        const int t = tb + s;
        // publish h_{t-1} (layers 0,1)
        if (l < 2 && t > 0) {
          u64 v = ((const u64*)(hbuf[t & 1]))[tid];
          AS(hpub + (size_t)((t - 1) % HR_) * 768 + tid, v);
        }
        // sample store t-1 (layer 2)
        if (l == 2 && t > 0 && tid < 16) {
          float sm = 0.f;
          #pragma unroll
          for (int uu = 0; uu < 12; ++uu) sm += plds[(t - 1) & 1][uu][tid];
          sample[(size_t)tid * S_ + (t - 1)] = sm;
        }
        f32x4 s4, c4;
        if (l == 0) {
          s4 = *(const f32x4*)(sinA + (size_t)t * 16 + lg * 4);
          c4 = *(const f32x4*)(cosA + (size_t)t * 16 + lg * 4);
        }
        // LDS -> A-frags
        s16x8 hf[6];
        #pragma unroll
        for (int kt = 0; kt < 6; ++kt)
          hf[kt] = *(const s16x8*)(hbuf[t & 1] + kt * 512 + rdoff);
        // MFMA
        f32x4 acc0 = {bh[0], bh[0], bh[0], bh[0]};
        f32x4 acc1 = {bh[1], bh[1], bh[1], bh[1]};
        f32x4 acc2 = {bh[2], bh[2], bh[2], bh[2]};
        #pragma unroll
        for (int kt = 0; kt < 6; ++kt) {
          acc0 = __builtin_amdgcn_mfma_f32_16x16x32_bf16(hf[kt], WH[0][kt], acc0, 0, 0, 0);
          acc1 = __builtin_amdgcn_mfma_f32_16x16x32_bf16(hf[kt], WH[1][kt], acc1, 0, 0, 0);
          acc2 = __builtin_amdgcn_mfma_f32_16x16x32_bf16(hf[kt], WH[2][kt], acc2, 0, 0, 0);
        }
        // gates
        f32x4 gr, gz, gn;
        if (l == 0) {
          gr = gbf[0] + s4 * wsn[0] + c4 * wcs[0];
          gz = gbf[1] + s4 * wsn[1] + c4 * wcs[1];
          gn = gbf[2] + s4 * wsn[2] + c4 * wcs[2];
        } else {
          union { u64 u; _Float16 hh[4]; } u0, u1, u2;
          u0.u = gpf[s >> 1][s & 1][0];
          u1.u = gpf[s >> 1][s & 1][1];
          u2.u = gpf[s >> 1][s & 1][2];
          #pragma unroll
          for (int j = 0; j < 4; ++j) { gr[j] = (float)u0.hh[j]; gz[j] = (float)u1.hh[j]; gn[j] = (float)u2.hh[j]; }
        }
        #pragma unroll
        for (int j = 0; j < 4; ++j) {
          float r = sigm(gr[j] + acc0[j]);
          float z = sigm(gz[j] + acc1[j]);
          float n = tanhx(gn[j] + r * acc2[j]);
          h[j] = n + z * (h[j] - n);
        }
        // refill gi prefetch after consumption (pair 0 at s==1, pair 1 at s==3)
        if (l > 0 && s == 1) {
          #pragma unroll
          for (int ss = 0; ss < 2; ++ss)
            #pragma unroll
            for (int g = 0; g < 3; ++g)
              gpf[0][ss][g] = AL(girp + (size_t)((tb + 4 + ss) % GR_) * 2304 + (12 * g + ut) * 64 + lane);
        }
        if (l > 0 && s == 3) {
          #pragma unroll
          for (int ss = 0; ss < 2; ++ss)
            #pragma unroll
            for (int g = 0; g < 3; ++g)
              gpf[1][ss][g] = AL(girp + (size_t)((tb + 6 + ss) % GR_) * 2304 + (12 * g + ut) * 64 + lane);
        }
        // write h' -> swizzled A-frag LDS (other buffer)
        {
          short* wb = hbuf[(t & 1) ^ 1] + kt_w * 512;
          #pragma unroll
          for (int j = 0; j < 4; ++j) {
            int b16 = ((4 * lg + j) | (q_ << 4)) ^ q_;
            wb[b16 * 8 + e_] = f2bf(h[j]);
          }
        }
        // head partials (layer 2)
        if (l == 2) {
          #pragma unroll
          for (int j = 0; j < 4; ++j) {
            float p = ow * h[j];
            p += __shfl_xor(p, 1); p += __shfl_xor(p, 2);
            p += __shfl_xor(p, 4); p += __shfl_xor(p, 8);
            if (l15 == 0) plds[t & 1][ut][lg * 4 + j] = p;
          }
        }
        // barrier / publish cadence
        if (l < 2 && (t & 15) == 15) {
          BARVM();
          if (tid == 0) AS(ctr + hctr, t);
        } else {
          BAR();
        }
      }
    }
    // ---- tail ----
    if (l < 2) {
      u64 v = ((const u64*)(hbuf[S_ & 1]))[tid];
      AS(hpub + (size_t)((S_ - 1) % HR_) * 768 + tid, v);
      asm volatile("s_waitcnt vmcnt(0)" ::: "memory");
      __syncthreads();
      if (tid == 0) AS(ctr + hctr, S_);
    } else if (tid < 16) {
      float sm = 0.f;
      #pragma unroll
      for (int uu = 0; uu < 12; ++uu) sm += plds[(S_ - 1) & 1][uu][tid];
      sample[(size_t)tid * S_ + (S_ - 1)] = sm;
    }
  } else {
    // ============================== GEMM ===================================
    const int m = (blk == 1) ? 1 : 2;
    const u64* src = (m == 1) ? (const u64*)(ws + OFF_H0) : (const u64*)(ws + OFF_H1);
    u64* dst = (m == 1) ? (u64*)(ws + OFF_GI1) : (u64*)(ws + OFF_GI2);
    const int hctr = (m == 1) ? C_H0 : C_H1;
    const int recc = (m == 1) ? C_H1 : C_RP2;
    const int gipc = (m == 1) ? C_GIP1 : C_GIP2;
    const int gemc = (m == 1) ? C_GEM1 : C_GEM2;
    const float* bih = (m == 1) ? bih1 : bih2;

    s16x8 WB[3][6];
    float bi[3];
    #pragma unroll
    for (int g = 0; g < 3; ++g) {
      const int nt = g * 12 + ut;
      #pragma unroll
      for (int kt = 0; kt < 6; ++kt)
        WB[g][kt] = *(const s16x8*)(wf + ((size_t)((m + 2) * 216) + nt * 6 + kt) * 512 + lane * 8);
      bi[g] = bih[g * 192 + 16 * ut + l15];
    }

    int havail = 0, recavail = 0;
    // prologue: wait h[0..15] and prime buf0 with steps 0..3
    if (tid == 0) {
      int v = AL(ctr + hctr);
      while (v < 16) { __builtin_amdgcn_s_sleep(2); v = AL(ctr + hctr); }
      bc = v;
    }
    __syncthreads();
    havail = bc;
    __syncthreads();
    {
      u64 R0 = AL(src + (size_t)0 * 768 + tid);
      u64 R1 = AL(src + (size_t)1 * 768 + tid);
      u64 R2 = AL(src + (size_t)2 * 768 + tid);
      u64 R3 = AL(src + (size_t)3 * 768 + tid);
      hstage[0][0][tid] = R0; hstage[0][1][tid] = R1;
      hstage[0][2][tid] = R2; hstage[0][3][tid] = R3;
    }
    __syncthreads();

    for (int G = 0; G < S_; G += 4) {
      const int cur = (G >> 2) & 1;
      if ((G & 7) == 0) {
        int tgt = G + 16; if (tgt > S_) tgt = S_;
        int tgt2 = G - 72; if (tgt2 < 0) tgt2 = 0;
        if (havail < tgt || recavail < tgt2) {
          if (tid == 0) {
            int v = AL(ctr + hctr);
            while (v < tgt) { __builtin_amdgcn_s_sleep(2); v = AL(ctr + hctr); }
            int w = AL(ctr + recc);
            while (w < tgt2) { __builtin_amdgcn_s_sleep(2); w = AL(ctr + recc); }
            bc = (v < S_ ? v : S_) * 32768 + 0;  // pack both? keep simple: two rounds
            bc = v;
          }
          __syncthreads();
          havail = bc;
          __syncthreads();
          if (tid == 0) {
            int w = AL(ctr + recc);
            bc = w;
          }
          __syncthreads();
          recavail = bc;
          __syncthreads();
        }
      }
      // issue loads for steps G+4..G+7
      u64 R0 = AL(src + (size_t)((G + 4) % HR_) * 768 + tid);
      u64 R1 = AL(src + (size_t)((G + 5) % HR_) * 768 + tid);
      u64 R2 = AL(src + (size_t)((G + 6) % HR_) * 768 + tid);
      u64 R3 = AL(src + (size_t)((G + 7) % HR_) * 768 + tid);
      // compute 4 steps from hstage[cur]
      #pragma unroll
      for (int s = 0; s < 4; ++s) {
        const int t = G + s;
        const short* hp = (const short*)(&hstage[cur][s][0]);
        s16x8 hf[6];
        #pragma unroll
        for (int kt = 0; kt < 6; ++kt)
          hf[kt] = *(const s16x8*)(hp + kt * 512 + rdoff);
        u64* dr = dst + (size_t)(t % GR_) * 2304 + lane;
        #pragma unroll
        for (int g = 0; g < 3; ++g) {
          f32x4 a = {bi[g], bi[g], bi[g], bi[g]};
          #pragma unroll
          for (int kt = 0; kt < 6; ++kt)
            a = __builtin_amdgcn_mfma_f32_16x16x32_bf16(hf[kt], WB[g][kt], a, 0, 0, 0);
          union { _Float16 hh[4]; u64 u; } pk;
          #pragma unroll
          for (int j = 0; j < 4; ++j) pk.hh[j] = (_Float16)a[j];
          AS(dr + (12 * g + ut) * 64, pk.u);
        }
      }
      // stage next group's h (compiler waits the R loads)
      hstage[cur ^ 1][0][tid] = R0; hstage[cur ^ 1][1][tid] = R1;
      hstage[cur ^ 1][2][tid] = R2; hstage[cur ^ 1][3][tid] = R3;
      if (((G + 4) & 7) == 0) {
        BARVM();
        if (tid == 0) {
          AS(ctr + gipc, G + 4);
          if (((G + 4) & 63) == 0) AS(ctr + gemc, G + 4);
        }
      } else {
        BAR();
      }
    }
  }
}

// ---------------------------------------------------------------------------
__global__ void k_final(char* ws, const float* __restrict__ noise,
                        const float* __restrict__ outb, const float* __restrict__ lgain,
                        float* __restrict__ out) {
  int i = blockIdx.x * 256 + threadIdx.x;
  if (i >= B_ * S_) return;
  int b = i / S_, s = i - b * S_;
  const float* sample = (const float*)(ws + OFF_SAMPLE);
  const float* vp     = (const float*)(ws + OFF_V);
  float smp = sample[(size_t)b * S_ + s] + outb[0];
  float v = vp[b * 50 + s / 160];
  float noisy = 0.6f * smp + 0.4f * (noise[(size_t)b * S_ + s] * 0.003f);
  float sm2 = v * smp + (1.f - v) * noisy;
  float wave = fminf(fmaxf(sm2, -1.f), 1.f);
  float gain = fminf(fmaxf(expf(lgain[0]), 0.5f), 1.5f);
  out[i] = 1.1f * tanhf(0.9f * gain * wave);
}

// ---------------------------------------------------------------------------
extern "C" void kernel_launch(void* const* d_in, const int* in_sizes, int n_in,
                              void* d_out, int out_size, void* d_ws, size_t ws_size,
                              hipStream_t stream) {
  (void)in_sizes; (void)n_in; (void)out_size; (void)ws_size;
  const float* feats  = (const float*)d_in[0];
  const float* noise  = (const float*)d_in[1];
  const float* pembed = (const float*)d_in[2];
  const float* fpw1   = (const float*)d_in[3];
  const float* fpb1   = (const float*)d_in[4];
  const float* fpw2   = (const float*)d_in[5];
  const float* fpb2   = (const float*)d_in[6];
  const float* outw   = (const float*)d_in[7];
  const float* outb   = (const float*)d_in[8];
  const float* lgain  = (const float*)d_in[9];
  const float* wih0   = (const float*)d_in[10];
  const float* whh0   = (const float*)d_in[11];
  const float* bih0   = (const float*)d_in[12];
  const float* bhh0   = (const float*)d_in[13];
  const float* wih1   = (const float*)d_in[14];
  const float* whh1   = (const float*)d_in[15];
  const float* bih1   = (const float*)d_in[16];
  const float* bhh1   = (const float*)d_in[17];
  const float* wih2   = (const float*)d_in[18];
  const float* whh2   = (const float*)d_in[19];
  const float* bih2   = (const float*)d_in[20];
  const float* bhh2   = (const float*)d_in[21];
  char* ws = (char*)d_ws;
  float* out = (float*)d_out;

  hipMemsetAsync(ws, 0, 4096, stream);
  hipLaunchKernelGGL(k_wprep, dim3(1296), dim3(64), 0, stream,
                     whh0, whh1, whh2, wih1, wih2, wih0, ws);
  hipLaunchKernelGGL(k_frame, dim3(B_ * 50), dim3(128), 0, stream,
                     feats, pembed, fpw1, fpb1, fpw2, fpb2, ws);
  hipLaunchKernelGGL(k_phase, dim3(B_), dim3(256), 0, stream, ws);
  hipLaunchKernelGGL(k_xpack, dim3(200), dim3(256), 0, stream, ws);
  hipLaunchKernelGGL(k_gru, dim3(5), dim3(768), 0, stream, ws, wih0, bih0,
                     bhh0, bhh1, bhh2, bih1, bih2, outw);
  hipLaunchKernelGGL(k_final, dim3((B_ * S_ + 255) / 256), dim3(256), 0, stream,
                     ws, noise, outb, lgain, out);
}

// Round 8
// 34853.101 us; speedup vs baseline: 1.1715x; 1.0084x over previous
//
#include <hip/hip_runtime.h>

// ---------------------------------------------------------------------------
// FarGAN wave head. R7 = R6 pipeline + THE aliasing fix:
//   separate __restrict__ params per buffer + asm-pinned weight fragments +
//   template<L> bodies. Weights must now be truly register-resident
//   (witness: VGPR_Count ~160 instead of 84).
// ---------------------------------------------------------------------------

#define B_ 16
#define S_ 8000
#define GRUIN_ 194
#define TWO_PI_F 6.2831853071795864769f

#define HR_ 256
#define GR_ 96

// ws offsets (bytes)
#define OFF_CTR    0
#define OFF_DV     4096
#define OFF_V      8192
#define OFF_SIN    16384      // 8000*16 f32
#define OFF_COS    528384
#define OFF_PE     1040384    // 16*50*64 f32
#define OFF_COND   1245184    // 16*200*128 f32
#define OFF_XF     2883584    // 200*6*512 bf16 (cond|pe A-frags)
#define OFF_WF     4112384    // 6*216*512 bf16 (B-frags)
#define OFF_H0     5439488    // 256*3072 bf16
#define OFF_H1     7012352
#define OFF_GI1    8585216    // 96*2304 u64 (f16 gi)
#define OFF_GI2    10354688
#define OFF_SAMPLE 12124160   // 16*8000 f32

// counters (int index)
#define C_H0   0
#define C_H1   32
#define C_GIP1 64
#define C_GIP2 96
#define C_GEM1 128
#define C_GEM2 160
#define C_RP2  192

typedef short s16x8 __attribute__((ext_vector_type(8)));
typedef float f32x4 __attribute__((ext_vector_type(4)));
typedef unsigned long long u64;

__device__ __forceinline__ short f2bf(float f) {
  unsigned u = __float_as_uint(f);
  return (short)((u + 0x7FFFu + ((u >> 16) & 1u)) >> 16);
}
__device__ __forceinline__ float sigm(float x) {
  return __fdividef(1.f, 1.f + __expf(-x));
}
__device__ __forceinline__ float tanhx(float x) {
  float e = __expf(2.f * x);
  return __fdividef(e - 1.f, e + 1.f);
}
#define AL(p)   __hip_atomic_load((p),  __ATOMIC_RELAXED, __HIP_MEMORY_SCOPE_AGENT)
#define AS(p,v) __hip_atomic_store((p), (v), __ATOMIC_RELAXED, __HIP_MEMORY_SCOPE_AGENT)
#define BAR()   asm volatile("s_waitcnt lgkmcnt(0)\n\ts_barrier" ::: "memory")
#define BARVM() asm volatile("s_waitcnt vmcnt(0) lgkmcnt(0)\n\ts_barrier" ::: "memory")
#define PIN(x)  asm volatile("" : "+v"(x))

// ---------------------------------------------------------------------------
__global__ void k_frame(const float* __restrict__ feats,
                        const float* __restrict__ pembed,
                        const float* __restrict__ w1, const float* __restrict__ b1,
                        const float* __restrict__ w2, const float* __restrict__ b2,
                        char* ws) {
  const int bt = blockIdx.x, tid = threadIdx.x;   // 128 thr
  float* dvp = (float*)(ws + OFF_DV);
  float* vp  = (float*)(ws + OFF_V);
  float* pep = (float*)(ws + OFF_PE);
  float* cnd = (float*)(ws + OFF_COND);
  __shared__ float fin[112];
  __shared__ float h1[256];
  __shared__ int   sidx;
  if (tid == 0) {
    float f0 = feats[bt * 48 + 46], vo = feats[bt * 48 + 47];
    float period = fminf(fmaxf(256.f * exp2f(-(f0 + 2.f)), 32.f), 255.f);
    int idx = (int)rintf(period) - 32;
    float f0hz = 16000.f / fmaxf(period, 1.f);
    float v = fminf(fmaxf(vo, 0.f), 1.f);
    float delta = TWO_PI_F * fmaxf(f0hz, 60.f) * (1.f / 16000.f);
    dvp[bt] = delta * v; vp[bt] = v; sidx = idx;
  }
  __syncthreads();
  if (tid < 48) fin[tid] = feats[bt * 48 + tid];
  if (tid < 64) { float pv = pembed[sidx * 64 + tid]; fin[48 + tid] = pv; pep[bt * 64 + tid] = pv; }
  __syncthreads();
  #pragma unroll
  for (int rr = 0; rr < 2; ++rr) {
    int r = tid + rr * 128;
    const float* wr = w1 + r * 112;
    float acc = b1[r];
    #pragma unroll 4
    for (int k = 0; k < 112; ++k) acc += wr[k] * fin[k];
    h1[r] = 0.5f * acc * (1.f + erff(acc * 0.70710678118654752440f));
  }
  __syncthreads();
  const int b = bt / 50, t = bt - b * 50;
  #pragma unroll
  for (int rr = 0; rr < 4; ++rr) {
    int r = tid + rr * 128;
    const float* wr = w2 + r * 256;
    float acc = b2[r];
    #pragma unroll 4
    for (int k = 0; k < 256; ++k) acc += wr[k] * h1[k];
    int sf = r >> 7, c = r & 127;
    cnd[((b * 200) + (t * 4 + sf)) * 128 + c] = acc;
  }
}

// ---------------------------------------------------------------------------
__global__ void k_phase(char* ws) {
  const int b = blockIdx.x, tid = threadIdx.x;    // 256 thr
  const float* dvp = (const float*)(ws + OFF_DV);
  float* sinA = (float*)(ws + OFF_SIN);
  float* cosA = (float*)(ws + OFF_COS);
  __shared__ float ps[200], dvs[200];
  if (tid == 0) {
    float c = 0.f;
    for (int ts = 0; ts < 200; ++ts) {
      float d = dvp[b * 50 + (ts >> 2)];
      dvs[ts] = d;
      float inc = d * 40.f;
      c = c + inc;
      ps[ts] = fmodf(c - inc, TWO_PI_F);
    }
  }
  __syncthreads();
  for (int i = tid; i < S_; i += 256) {
    int ts = i / 40, k = i - ts * 40;
    float ph = ps[ts] + dvs[ts] * (float)k;
    sinA[(size_t)i * 16 + b] = sinf(ph);
    cosA[(size_t)i * 16 + b] = cosf(ph);
  }
}

// ---------------------------------------------------------------------------
__global__ void k_xpack(char* ws) {
  const int ts = blockIdx.x, tid = threadIdx.x;   // 200 blocks, 256 thr
  const int t = ts >> 2;
  const float* cnd = (const float*)(ws + OFF_COND);
  const float* pep = (const float*)(ws + OFF_PE);
  short* xf = (short*)(ws + OFF_XF) + (size_t)ts * 3072;
  for (int i = tid; i < 3072; i += 256) {
    int kt = i >> 9, r = i & 511, lane = r >> 3, e = r & 7;
    int k = kt * 32 + 16 * (e >> 2) + 4 * (lane >> 4) + (e & 3);
    int b = lane & 15;
    float v = (k < 128) ? cnd[((b * 200) + ts) * 128 + k]
                        : pep[(b * 50 + t) * 64 + (k - 128)];
    xf[i] = f2bf(v);
  }
}

// ---------------------------------------------------------------------------
// pack 6 matrices: 0=whh0 1=whh1 2=whh2 3=wih1 4=wih2 5=wih0[:, :192]
__global__ void k_wprep(const float* __restrict__ whh0, const float* __restrict__ whh1,
                        const float* __restrict__ whh2, const float* __restrict__ wih1,
                        const float* __restrict__ wih2, const float* __restrict__ wih0,
                        char* ws) {
  const int blk = blockIdx.x;           // 1296 blocks, 64 thr
  const int mat = blk / 216, rem = blk - mat * 216;
  const int nt = rem / 6, kt = rem - nt * 6;
  const int lane = threadIdx.x;
  const float* W; int stride;
  if (mat == 0)      { W = whh0; stride = 192; }
  else if (mat == 1) { W = whh1; stride = 192; }
  else if (mat == 2) { W = whh2; stride = 192; }
  else if (mat == 3) { W = wih1; stride = 192; }
  else if (mat == 4) { W = wih2; stride = 192; }
  else               { W = wih0; stride = 194; }
  short* dst = (short*)(ws + OFF_WF) + ((size_t)(mat * 216) + nt * 6 + kt) * 512 + lane * 8;
  const int row = nt * 16 + (lane & 15);
  const int g = lane >> 4;
  #pragma unroll
  for (int e = 0; e < 8; ++e) {
    int k = kt * 32 + 16 * (e >> 2) + 4 * g + (e & 3);
    dst[e] = f2bf(W[(size_t)row * stride + k]);
  }
}

// ---------------------------------------------------------------------------
// recurrent body, template on layer
// ---------------------------------------------------------------------------
template<int L>
__device__ __forceinline__ void rec_body(
    int* __restrict__ ctr, const short* __restrict__ wf,
    const short* __restrict__ xfb,
    const float* __restrict__ sinA, const float* __restrict__ cosA,
    u64* __restrict__ hpub, const u64* __restrict__ girp,
    float* __restrict__ sample,
    const float* __restrict__ wih0, const float* __restrict__ bih0,
    const float* __restrict__ bhh, const float* __restrict__ outw,
    short* hbuf, float* plds, volatile int* bcs,
    const int tid, const int ut, const int lane, const int lg, const int l15,
    const int rdoff) {
  const int hctr = (L == 0) ? C_H0 : C_H1;
  const int gipc = (L == 1) ? C_GIP1 : C_GIP2;
  const int gemc = (L == 0) ? C_GEM1 : C_GEM2;

  s16x8 WH[3][6];
  float bh[3];
  #pragma unroll
  for (int g = 0; g < 3; ++g) {
    const int nt = g * 12 + ut;
    #pragma unroll
    for (int kt = 0; kt < 6; ++kt)
      WH[g][kt] = *(const s16x8*)(wf + ((size_t)(L * 216) + nt * 6 + kt) * 512 + lane * 8);
    bh[g] = bhh[g * 192 + 16 * ut + l15];
  }
  #pragma unroll
  for (int g = 0; g < 3; ++g) {
    #pragma unroll
    for (int kt = 0; kt < 6; ++kt) PIN(WH[g][kt]);
    PIN(bh[g]);
  }

  float wsn[3], wcs[3], bi0[3];
  if constexpr (L == 0) {
    #pragma unroll
    for (int g = 0; g < 3; ++g) {
      int row = g * 192 + 16 * ut + l15;
      wsn[g] = wih0[(size_t)row * GRUIN_ + 192];
      wcs[g] = wih0[(size_t)row * GRUIN_ + 193];
      bi0[g] = bih0[row];
      PIN(wsn[g]); PIN(wcs[g]); PIN(bi0[g]);
    }
  }
  float ow = 0.f;
  if constexpr (L == 2) { ow = outw[16 * ut + l15]; PIN(ow); }

  for (int i = tid; i < 1536; i += 768) ((u64*)hbuf)[i] = 0;
  __syncthreads();

  f32x4 h = {0, 0, 0, 0};
  f32x4 gbf[3];
  u64 gpf[2][2][3];
  int giavail = 0, gemavail = 0;
  const int kt_w = ut >> 1;
  const int e_   = ((ut & 1) << 2) | (l15 & 3);
  const int q_   = l15 >> 2;

  if constexpr (L > 0) {
    if (tid == 0) {
      int v = AL(ctr + gipc);
      while (v < 16) { __builtin_amdgcn_s_sleep(2); v = AL(ctr + gipc); }
      bcs[0] = v;
    }
    __syncthreads();
    giavail = bcs[0];
    __syncthreads();
    #pragma unroll
    for (int p = 0; p < 2; ++p)
      #pragma unroll
      for (int ss = 0; ss < 2; ++ss)
        #pragma unroll
        for (int g = 0; g < 3; ++g)
          gpf[p][ss][g] = AL(girp + (size_t)(2 * p + ss) * 2304 + (12 * g + ut) * 64 + lane);
  }

  for (int tb = 0; tb < S_; tb += 4) {
    // ---- waits (cached watermarks) ----
    if constexpr (L > 0) {
      if ((tb & 7) == 0) {
        int tgt = tb + 16; if (tgt > S_) tgt = S_;
        if (giavail < tgt) {
          if (tid == 0) {
            int v = AL(ctr + gipc);
            while (v < tgt) { __builtin_amdgcn_s_sleep(2); v = AL(ctr + gipc); }
            bcs[0] = v;
          }
          __syncthreads(); giavail = bcs[0]; __syncthreads();
        }
      }
    }
    if constexpr (L < 2) {
      if ((tb & 63) == 0 && tb >= 192) {
        int tgt = tb - 128;
        if (gemavail < tgt) {
          if (tid == 0) {
            int v = AL(ctr + gemc);
            while (v < tgt) { __builtin_amdgcn_s_sleep(2); v = AL(ctr + gemc); }
            bcs[0] = v;
          }
          __syncthreads(); gemavail = bcs[0]; __syncthreads();
        }
      }
    }
    if constexpr (L == 2) {
      if ((tb & 63) == 0 && tid == 0) AS(ctr + C_RP2, tb);
    }

    // ---- gbase GEMM every 40 steps (layer 0) ----
    if constexpr (L == 0) {
      if (tb % 40 == 0) {
        int ts = tb / 40;
        const short* xp = xfb + (size_t)ts * 3072;
        s16x8 xfr[6];
        #pragma unroll
        for (int kt = 0; kt < 6; ++kt) xfr[kt] = *(const s16x8*)(xp + kt * 512 + lane * 8);
        #pragma unroll
        for (int g = 0; g < 3; ++g) {
          const int nt = g * 12 + ut;
          f32x4 a = {bi0[g], bi0[g], bi0[g], bi0[g]};
          #pragma unroll
          for (int kt = 0; kt < 6; ++kt) {
            s16x8 wfr = *(const s16x8*)(wf + ((size_t)(5 * 216) + nt * 6 + kt) * 512 + lane * 8);
            a = __builtin_amdgcn_mfma_f32_16x16x32_bf16(xfr[kt], wfr, a, 0, 0, 0);
          }
          gbf[g] = a;
        }
      }
    }

    // ---- 4 substeps ----
    #pragma unroll
    for (int s = 0; s < 4; ++s) {
      const int t = tb + s;
      if constexpr (L < 2) {
        if (t > 0) {
          u64 v = ((const u64*)hbuf)[(t & 1) * 768 + tid];
          AS(hpub + (size_t)((t - 1) % HR_) * 768 + tid, v);
        }
      }
      if constexpr (L == 2) {
        if (t > 0 && tid < 16) {
          float sm = 0.f;
          #pragma unroll
          for (int uu = 0; uu < 12; ++uu) sm += plds[(((t - 1) & 1) * 12 + uu) * 16 + tid];
          sample[(size_t)tid * S_ + (t - 1)] = sm;
        }
      }
      f32x4 s4, c4;
      if constexpr (L == 0) {
        s4 = *(const f32x4*)(sinA + (size_t)t * 16 + lg * 4);
        c4 = *(const f32x4*)(cosA + (size_t)t * 16 + lg * 4);
      }
      // LDS -> A-frags (swizzled)
      s16x8 hf[6];
      #pragma unroll
      for (int kt = 0; kt < 6; ++kt)
        hf[kt] = *(const s16x8*)(hbuf + (t & 1) * 3072 + kt * 512 + rdoff);
      // MFMA (weights pinned in VGPRs)
      f32x4 acc0 = {bh[0], bh[0], bh[0], bh[0]};
      f32x4 acc1 = {bh[1], bh[1], bh[1], bh[1]};
      f32x4 acc2 = {bh[2], bh[2], bh[2], bh[2]};
      #pragma unroll
      for (int kt = 0; kt < 6; ++kt) {
        acc0 = __builtin_amdgcn_mfma_f32_16x16x32_bf16(hf[kt], WH[0][kt], acc0, 0, 0, 0);
        acc1 = __builtin_amdgcn_mfma_f32_16x16x32_bf16(hf[kt], WH[1][kt], acc1, 0, 0, 0);
        acc2 = __builtin_amdgcn_mfma_f32_16x16x32_bf16(hf[kt], WH[2][kt], acc2, 0, 0, 0);
      }
      // gates
      f32x4 gr, gz, gn;
      if constexpr (L == 0) {
        gr = gbf[0] + s4 * wsn[0] + c4 * wcs[0];
        gz = gbf[1] + s4 * wsn[1] + c4 * wcs[1];
        gn = gbf[2] + s4 * wsn[2] + c4 * wcs[2];
      } else {
        union { u64 u; _Float16 hh[4]; } u0, u1, u2;
        u0.u = gpf[s >> 1][s & 1][0];
        u1.u = gpf[s >> 1][s & 1][1];
        u2.u = gpf[s >> 1][s & 1][2];
        #pragma unroll
        for (int j = 0; j < 4; ++j) { gr[j] = (float)u0.hh[j]; gz[j] = (float)u1.hh[j]; gn[j] = (float)u2.hh[j]; }
      }
      #pragma unroll
      for (int j = 0; j < 4; ++j) {
        float r = sigm(gr[j] + acc0[j]);
        float z = sigm(gz[j] + acc1[j]);
        float n = tanhx(gn[j] + r * acc2[j]);
        h[j] = n + z * (h[j] - n);
      }
      // refill gi prefetch
      if constexpr (L > 0) {
        if (s == 1) {
          #pragma unroll
          for (int ss = 0; ss < 2; ++ss)
            #pragma unroll
            for (int g = 0; g < 3; ++g)
              gpf[0][ss][g] = AL(girp + (size_t)((tb + 4 + ss) % GR_) * 2304 + (12 * g + ut) * 64 + lane);
        }
        if (s == 3) {
          #pragma unroll
          for (int ss = 0; ss < 2; ++ss)
            #pragma unroll
            for (int g = 0; g < 3; ++g)
              gpf[1][ss][g] = AL(girp + (size_t)((tb + 6 + ss) % GR_) * 2304 + (12 * g + ut) * 64 + lane);
        }
      }
      // write h' -> swizzled A-frag LDS (other buffer)
      {
        short* wb = hbuf + ((t & 1) ^ 1) * 3072 + kt_w * 512;
        #pragma unroll
        for (int j = 0; j < 4; ++j) {
          int b16 = ((4 * lg + j) | (q_ << 4)) ^ q_;
          wb[b16 * 8 + e_] = f2bf(h[j]);
        }
      }
      // head partials (layer 2)
      if constexpr (L == 2) {
        #pragma unroll
        for (int j = 0; j < 4; ++j) {
          float p = ow * h[j];
          p += __shfl_xor(p, 1); p += __shfl_xor(p, 2);
          p += __shfl_xor(p, 4); p += __shfl_xor(p, 8);
          if (l15 == 0) plds[((t & 1) * 12 + ut) * 16 + lg * 4 + j] = p;
        }
      }
      // barrier / publish cadence
      if (L < 2 && (t & 15) == 15) {
        BARVM();
        if (tid == 0) AS(ctr + hctr, t);
      } else {
        BAR();
      }
    }
  }
  // ---- tail ----
  if constexpr (L < 2) {
    u64 v = ((const u64*)hbuf)[(S_ & 1) * 768 + tid];
    AS(hpub + (size_t)((S_ - 1) % HR_) * 768 + tid, v);
    asm volatile("s_waitcnt vmcnt(0)" ::: "memory");
    __syncthreads();
    if (tid == 0) AS(ctr + hctr, S_);
  } else {
    if (tid < 16) {
      float sm = 0.f;
      #pragma unroll
      for (int uu = 0; uu < 12; ++uu) sm += plds[(((S_ - 1) & 1) * 12 + uu) * 16 + tid];
      sample[(size_t)tid * S_ + (S_ - 1)] = sm;
    }
  }
}

// ---------------------------------------------------------------------------
// GEMM body, template on target layer M (1 or 2)
// ---------------------------------------------------------------------------
template<int M>
__device__ __forceinline__ void gemm_body(
    int* __restrict__ ctr, const short* __restrict__ wf,
    const u64* __restrict__ src, u64* __restrict__ dst,
    const float* __restrict__ bih,
    u64* hstage, volatile int* bcs,
    const int tid, const int ut, const int lane, const int l15, const int rdoff) {
  const int hctr = (M == 1) ? C_H0 : C_H1;
  const int recc = (M == 1) ? C_H1 : C_RP2;
  const int gipc = (M == 1) ? C_GIP1 : C_GIP2;
  const int gemc = (M == 1) ? C_GEM1 : C_GEM2;

  s16x8 WB[3][6];
  float bi[3];
  #pragma unroll
  for (int g = 0; g < 3; ++g) {
    const int nt = g * 12 + ut;
    #pragma unroll
    for (int kt = 0; kt < 6; ++kt)
      WB[g][kt] = *(const s16x8*)(wf + ((size_t)((M + 2) * 216) + nt * 6 + kt) * 512 + lane * 8);
    bi[g] = bih[g * 192 + 16 * ut + l15];
  }
  #pragma unroll
  for (int g = 0; g < 3; ++g) {
    #pragma unroll
    for (int kt = 0; kt < 6; ++kt) PIN(WB[g][kt]);
    PIN(bi[g]);
  }

  int havail = 0, recavail = 0;
  if (tid == 0) {
    int v = AL(ctr + hctr);
    while (v < 16) { __builtin_amdgcn_s_sleep(2); v = AL(ctr + hctr); }
    bcs[0] = v;
  }
  __syncthreads();
  havail = bcs[0];
  __syncthreads();
  {
    u64 R0 = AL(src + (size_t)0 * 768 + tid);
    u64 R1 = AL(src + (size_t)1 * 768 + tid);
    u64 R2 = AL(src + (size_t)2 * 768 + tid);
    u64 R3 = AL(src + (size_t)3 * 768 + tid);
    hstage[0 * 768 + tid] = R0; hstage[1 * 768 + tid] = R1;
    hstage[2 * 768 + tid] = R2; hstage[3 * 768 + tid] = R3;
  }
  __syncthreads();

  for (int G = 0; G < S_; G += 4) {
    const int cur = (G >> 2) & 1;
    if ((G & 7) == 0) {
      int tgt = G + 16; if (tgt > S_) tgt = S_;
      int tgt2 = G - 72; if (tgt2 < 0) tgt2 = 0;
      if (havail < tgt || recavail < tgt2) {
        if (tid == 0) {
          int v = AL(ctr + hctr);
          while (v < tgt) { __builtin_amdgcn_s_sleep(2); v = AL(ctr + hctr); }
          int w2 = AL(ctr + recc);
          while (w2 < tgt2) { __builtin_amdgcn_s_sleep(2); w2 = AL(ctr + recc); }
          bcs[0] = v; bcs[1] = w2;
        }
        __syncthreads();
        havail = bcs[0]; recavail = bcs[1];
        __syncthreads();
      }
    }
    // issue loads for steps G+4..G+7
    u64 R0 = AL(src + (size_t)((G + 4) % HR_) * 768 + tid);
    u64 R1 = AL(src + (size_t)((G + 5) % HR_) * 768 + tid);
    u64 R2 = AL(src + (size_t)((G + 6) % HR_) * 768 + tid);
    u64 R3 = AL(src + (size_t)((G + 7) % HR_) * 768 + tid);
    // compute 4 steps from hstage[cur]
    #pragma unroll
    for (int s = 0; s < 4; ++s) {
      const int t = G + s;
      const short* hp = (const short*)(hstage + (cur * 4 + s) * 768);
      s16x8 hf[6];
      #pragma unroll
      for (int kt = 0; kt < 6; ++kt)
        hf[kt] = *(const s16x8*)(hp + kt * 512 + rdoff);
      u64* dr = dst + (size_t)(t % GR_) * 2304 + lane;
      #pragma unroll
      for (int g = 0; g < 3; ++g) {
        f32x4 a = {bi[g], bi[g], bi[g], bi[g]};
        #pragma unroll
        for (int kt = 0; kt < 6; ++kt)
          a = __builtin_amdgcn_mfma_f32_16x16x32_bf16(hf[kt], WB[g][kt], a, 0, 0, 0);
        union { _Float16 hh[4]; u64 u; } pk;
        #pragma unroll
        for (int j = 0; j < 4; ++j) pk.hh[j] = (_Float16)a[j];
        AS(dr + (12 * g + ut) * 64, pk.u);
      }
    }
    // stage next group's h
    hstage[((cur ^ 1) * 4 + 0) * 768 + tid] = R0;
    hstage[((cur ^ 1) * 4 + 1) * 768 + tid] = R1;
    hstage[((cur ^ 1) * 4 + 2) * 768 + tid] = R2;
    hstage[((cur ^ 1) * 4 + 3) * 768 + tid] = R3;
    if (((G + 4) & 7) == 0) {
      BARVM();
      if (tid == 0) {
        AS(ctr + gipc, G + 4);
        if (((G + 4) & 63) == 0) AS(ctr + gemc, G + 4);
      }
    } else {
      BAR();
    }
  }
}

// ---------------------------------------------------------------------------
__global__ __launch_bounds__(768, 1)
void k_gru(int* __restrict__ ctr, const short* __restrict__ wf,
           const short* __restrict__ xfb,
           const float* __restrict__ sinA, const float* __restrict__ cosA,
           u64* __restrict__ h0, u64* __restrict__ h1,
           u64* __restrict__ gi1, u64* __restrict__ gi2,
           float* __restrict__ sample,
           const float* __restrict__ wih0, const float* __restrict__ bih0,
           const float* __restrict__ bhh0, const float* __restrict__ bhh1,
           const float* __restrict__ bhh2, const float* __restrict__ bih1,
           const float* __restrict__ bih2, const float* __restrict__ outw) {
  const int blk = blockIdx.x;
  const int tid = threadIdx.x;
  const int ut = tid >> 6, lane = tid & 63, lg = lane >> 4, l15 = lane & 15;
  const int rdoff = (lane ^ ((lane >> 4) & 3)) * 8;

  __shared__ __align__(16) u64 hstage[2 * 4 * 768];   // 48KB (GEMM)
  __shared__ __align__(16) short hbuf[2 * 3072];      // 12KB (rec)
  __shared__ float plds[2 * 12 * 16];
  __shared__ int bcs[2];

  if (blk == 0)
    rec_body<0>(ctr, wf, xfb, sinA, cosA, h0, gi1, sample, wih0, bih0, bhh0, outw,
                hbuf, plds, bcs, tid, ut, lane, lg, l15, rdoff);
  else if (blk == 2)
    rec_body<1>(ctr, wf, xfb, sinA, cosA, h1, gi1, sample, wih0, bih0, bhh1, outw,
                hbuf, plds, bcs, tid, ut, lane, lg, l15, rdoff);
  else if (blk == 4)
    rec_body<2>(ctr, wf, xfb, sinA, cosA, h1, gi2, sample, wih0, bih0, bhh2, outw,
                hbuf, plds, bcs, tid, ut, lane, lg, l15, rdoff);
  else if (blk == 1)
    gemm_body<1>(ctr, wf, h0, gi1, bih1, hstage, bcs, tid, ut, lane, l15, rdoff);
  else
    gemm_body<2>(ctr, wf, h1, gi2, bih2, hstage, bcs, tid, ut, lane, l15, rdoff);
}

// ---------------------------------------------------------------------------
__global__ void k_final(char* ws, const float* __restrict__ noise,
                        const float* __restrict__ outb, const float* __restrict__ lgain,
                        float* __restrict__ out) {
  int i = blockIdx.x * 256 + threadIdx.x;
  if (i >= B_ * S_) return;
  int b = i / S_, s = i - b * S_;
  const float* sample = (const float*)(ws + OFF_SAMPLE);
  const float* vp     = (const float*)(ws + OFF_V);
  float smp = sample[(size_t)b * S_ + s] + outb[0];
  float v = vp[b * 50 + s / 160];
  float noisy = 0.6f * smp + 0.4f * (noise[(size_t)b * S_ + s] * 0.003f);
  float sm2 = v * smp + (1.f - v) * noisy;
  float wave = fminf(fmaxf(sm2, -1.f), 1.f);
  float gain = fminf(fmaxf(expf(lgain[0]), 0.5f), 1.5f);
  out[i] = 1.1f * tanhf(0.9f * gain * wave);
}

// ---------------------------------------------------------------------------
extern "C" void kernel_launch(void* const* d_in, const int* in_sizes, int n_in,
                              void* d_out, int out_size, void* d_ws, size_t ws_size,
                              hipStream_t stream) {
  (void)in_sizes; (void)n_in; (void)out_size; (void)ws_size;
  const float* feats  = (const float*)d_in[0];
  const float* noise  = (const float*)d_in[1];
  const float* pembed = (const float*)d_in[2];
  const float* fpw1   = (const float*)d_in[3];
  const float* fpb1   = (const float*)d_in[4];
  const float* fpw2   = (const float*)d_in[5];
  const float* fpb2   = (const float*)d_in[6];
  const float* outw   = (const float*)d_in[7];
  const float* outb   = (const float*)d_in[8];
  const float* lgain  = (const float*)d_in[9];
  const float* wih0   = (const float*)d_in[10];
  const float* whh0   = (const float*)d_in[11];
  const float* bih0   = (const float*)d_in[12];
  const float* bhh0   = (const float*)d_in[13];
  const float* wih1   = (const float*)d_in[14];
  const float* whh1   = (const float*)d_in[15];
  const float* bih1   = (const float*)d_in[16];
  const float* bhh1   = (const float*)d_in[17];
  const float* wih2   = (const float*)d_in[18];
  const float* whh2   = (const float*)d_in[19];
  const float* bih2   = (const float*)d_in[20];
  const float* bhh2   = (const float*)d_in[21];
  char* ws = (char*)d_ws;
  float* out = (float*)d_out;

  int*   ctr  = (int*)(ws + OFF_CTR);
  short* wfp  = (short*)(ws + OFF_WF);
  short* xfp  = (short*)(ws + OFF_XF);
  float* sinp = (float*)(ws + OFF_SIN);
  float* cosp = (float*)(ws + OFF_COS);
  u64*   h0p  = (u64*)(ws + OFF_H0);
  u64*   h1p  = (u64*)(ws + OFF_H1);
  u64*   gi1p = (u64*)(ws + OFF_GI1);
  u64*   gi2p = (u64*)(ws + OFF_GI2);
  float* smp  = (float*)(ws + OFF_SAMPLE);

  hipMemsetAsync(ws, 0, 4096, stream);
  hipLaunchKernelGGL(k_wprep, dim3(1296), dim3(64), 0, stream,
                     whh0, whh1, whh2, wih1, wih2, wih0, ws);
  hipLaunchKernelGGL(k_frame, dim3(B_ * 50), dim3(128), 0, stream,
                     feats, pembed, fpw1, fpb1, fpw2, fpb2, ws);
  hipLaunchKernelGGL(k_phase, dim3(B_), dim3(256), 0, stream, ws);
  hipLaunchKernelGGL(k_xpack, dim3(200), dim3(256), 0, stream, ws);
  hipLaunchKernelGGL(k_gru, dim3(5), dim3(768), 0, stream,
                     ctr, wfp, xfp, sinp, cosp, h0p, h1p, gi1p, gi2p, smp,
                     wih0, bih0, bhh0, bhh1, bhh2, bih1, bih2, outw);
  hipLaunchKernelGGL(k_final, dim3((B_ * S_ + 255) / 256), dim3(256), 0, stream,
                     ws, noise, outb, lgain, out);
}